// Round 13
// baseline (342.219 us; speedup 1.0000x reference)
//
#include <hip/hip_runtime.h>

#define N_NODES 50000
#define N_EDGES 800000
#define DIM 128
#define NCLS 40

// chunked CSR build
#define NCHUNK 64
#define CE 12500           // NCHUNK*CE == N_EDGES exactly
#define HALF_N 25088       // nodes per half (2*WHALF)
#define WHALF 12544        // packed u32 words per half (= 49*256)
#define SCAN_B 98          // cscan/scan_final blocks (2 halves * 49)
#define N_PAD 50432        // >= 2*HALF_N padded node arrays

typedef __bf16 bf16x8_t __attribute__((ext_vector_type(8)));
typedef unsigned short us8_t __attribute__((ext_vector_type(8)));
typedef float f32x4_t __attribute__((ext_vector_type(4)));
typedef float f32x2_t __attribute__((ext_vector_type(2)));

static __device__ __forceinline__ float b2f(unsigned short h) {
    unsigned u = ((unsigned)h) << 16;
    return __builtin_bit_cast(float, u);
}
static __device__ __forceinline__ unsigned short f2b(float f) {
    unsigned u = __builtin_bit_cast(unsigned, f);
    u += 0x7FFFu + ((u >> 16) & 1u);   // RNE; values finite O(1)
    return (unsigned short)(u >> 16);
}

// ---------------- fused prep: f32->bf16 shadow of h (blocks 0..3124) + weight repack (blocks 3125..3300) ----------------
__global__ __launch_bounds__(256) void prep(const float* __restrict__ hin,
                                            unsigned short* __restrict__ hb16,
                                            const float* __restrict__ w0,
                                            const float* __restrict__ w1,
                                            const float* __restrict__ w2,
                                            const float* __restrict__ wp,
                                            unsigned short* __restrict__ f0h,
                                            unsigned short* __restrict__ f0l,
                                            unsigned short* __restrict__ f1h,
                                            unsigned short* __restrict__ f1l,
                                            unsigned short* __restrict__ f2h,
                                            unsigned short* __restrict__ f2l,
                                            unsigned short* __restrict__ fph,
                                            unsigned short* __restrict__ fpl) {
    if (blockIdx.x < 3125) {
        size_t e0 = ((size_t)blockIdx.x * 256 + threadIdx.x) * 8;   // 6.4M exact
        f32x4_t v0 = *(const f32x4_t*)(hin + e0);
        f32x4_t v1 = *(const f32x4_t*)(hin + e0 + 4);
        us8_t o;
        #pragma unroll
        for (int j = 0; j < 4; ++j) { o[j] = f2b(v0[j]); o[4 + j] = f2b(v1[j]); }
        *(us8_t*)(hb16 + e0) = o;
        return;
    }
    int t = (blockIdx.x - 3125) * 256 + threadIdx.x;
    const float* src;
    unsigned short *dh, *dl;
    int idx, ncols;
    if (t < 16384)      { src = w0; dh = f0h; dl = f0l; idx = t;         ncols = 128; }
    else if (t < 32768) { src = w1; dh = f1h; dl = f1l; idx = t - 16384; ncols = 128; }
    else if (t < 38912) { src = w2; dh = f2h; dl = f2l; idx = t - 32768; ncols = 48; }
    else if (t < 45056) { src = wp; dh = fph; dl = fpl; idx = t - 38912; ncols = 48; }
    else return;
    int k = idx / ncols, n = idx - k * ncols;
    float v;
    if (ncols == 128) v = src[k * 128 + n];
    else              v = (n < NCLS) ? src[k * NCLS + n] : 0.f;
    int nt = n >> 4, m = n & 15, kt = k >> 5, quad = (k >> 3) & 3, j = k & 7;
    int off = ((nt * 4 + kt) * 64 + quad * 16 + m) * 8 + j;
    unsigned short hi = f2b(v);
    dh[off] = hi;
    dl[off] = f2b(v - b2f(hi));
}

// ---------------- per-chunk per-node counts + per-edge rank (LDS atomics); blockIdx.y = half ----------------
__global__ __launch_bounds__(256) void chunk_count(const int* __restrict__ dst,
                                                   unsigned* __restrict__ cnt,
                                                   unsigned short* __restrict__ ranks) {
    __shared__ unsigned lds[WHALF];   // 50 KB
    int c = blockIdx.x, h = blockIdx.y, tid = threadIdx.x;
    for (int w = tid; w < WHALF; w += 256) lds[w] = 0;
    __syncthreads();
    int base = c * CE;
    for (int k = tid; k < CE; k += 256) {
        int e = base + k;
        int local = dst[e] - h * HALF_N;
        if (local >= 0 && local < HALF_N) {
            int sh = (local & 1) * 16;
            unsigned old = atomicAdd(&lds[local >> 1], 1u << sh);
            ranks[e] = (unsigned short)((old >> sh) & 0xFFFFu);
        }
    }
    __syncthreads();
    unsigned* out = cnt + ((size_t)(h * NCHUNK + c)) * WHALF;
    for (int w = tid; w < WHALF; w += 256) out[w] = lds[w];
}

// ---------------- scan over chunk axis ----------------
__global__ __launch_bounds__(256) void cscan(unsigned* __restrict__ cnt,
                                             unsigned* __restrict__ degp,
                                             int* __restrict__ partial) {
    __shared__ int lds[256];
    int b = blockIdx.x;
    int h = b / 49;
    int w = (b % 49) * 256 + threadIdx.x;
    unsigned acc = 0;
    for (int c = 0; c < NCHUNK; ++c) {
        size_t idx = ((size_t)(h * NCHUNK + c)) * WHALF + w;
        unsigned v = cnt[idx];
        cnt[idx] = acc;          // exclusive prefix over chunks (packed halves)
        acc += v;
    }
    degp[h * WHALF + w] = acc;
    lds[threadIdx.x] = (int)(acc & 0xFFFFu) + (int)(acc >> 16);
    __syncthreads();
    #pragma unroll
    for (int off = 128; off > 0; off >>= 1) {
        if (threadIdx.x < off) lds[threadIdx.x] += lds[threadIdx.x + off];
        __syncthreads();
    }
    if (threadIdx.x == 0) partial[b] = lds[0];
}

// ---------------- final node-axis scan (absorbs the 98-partial block scan): rs / deg / dinv ----------------
__global__ __launch_bounds__(256) void scan_final(const unsigned* __restrict__ degp,
                                                  const int* __restrict__ partial,
                                                  int* __restrict__ rs,
                                                  int* __restrict__ deg,
                                                  float* __restrict__ dinv) {
    __shared__ int lds[256];
    __shared__ int pscan[128];
    int b = blockIdx.x;
    int h = b / 49;
    int tid = threadIdx.x;
    // redundant small scan of the 98 block partials (exclusive) — kills one launch
    if (tid < 128) pscan[tid] = (tid < SCAN_B) ? partial[tid] : 0;
    __syncthreads();
    #pragma unroll
    for (int off = 1; off < 128; off <<= 1) {
        int v = 0;
        if (tid < 128) v = pscan[tid];
        int add = (tid < 128 && tid >= off) ? pscan[tid - off] : 0;
        __syncthreads();
        if (tid < 128) pscan[tid] = v + add;
        __syncthreads();
    }
    int blk_off = (b == 0) ? 0 : pscan[b - 1];

    int w = (b % 49) * 256 + tid;
    unsigned dp = degp[h * WHALF + w];
    int lo = (int)(dp & 0xFFFFu), hi = (int)(dp >> 16);
    int s = lo + hi;
    lds[tid] = s;
    __syncthreads();
    #pragma unroll
    for (int off = 1; off < 256; off <<= 1) {
        int v = lds[tid];
        int add = (tid >= off) ? lds[tid - off] : 0;
        __syncthreads();
        lds[tid] = v + add;
        __syncthreads();
    }
    int excl = blk_off + lds[tid] - s;
    int n0 = h * HALF_N + 2 * w;
    rs[n0] = excl;
    rs[n0 + 1] = excl + lo;
    deg[n0] = lo;
    deg[n0 + 1] = hi;
    dinv[n0] = (lo > 0) ? (1.0f / (float)lo) : 0.0f;
    dinv[n0 + 1] = (hi > 0) ? (1.0f / (float)hi) : 0.0f;
}

// ---------------- CSR fill: pure scatter, no atomics ----------------
__global__ __launch_bounds__(256) void fill3(const int* __restrict__ src,
                                             const int* __restrict__ dst,
                                             const float* __restrict__ mask,
                                             const unsigned* __restrict__ cnt,
                                             const int* __restrict__ rs,
                                             const unsigned short* __restrict__ ranks,
                                             unsigned* __restrict__ csr) {
    int e = blockIdx.x * 256 + threadIdx.x;
    if (e >= N_EDGES) return;
    int d = dst[e];
    int c = e / CE;
    int h = (d >= HALF_N) ? 1 : 0;
    int local = d - h * HALF_N;
    int sh = (local & 1) * 16;
    unsigned cw = cnt[((size_t)(h * NCHUNK + c)) * WHALF + (local >> 1)];
    int pos = rs[d] + (int)((cw >> sh) & 0xFFFFu) + (int)ranks[e];
    csr[pos] = (unsigned)src[e] | ((unsigned)f2b(mask[e]) << 16);
}

// ---------------- mean aggregation: bf16 gather + f32 residual (batch-16, proven) ----------------
// NT store for xin: read-once stream, keep L2 for the bf16 gather table
__global__ __launch_bounds__(256) void agg_kernel(const unsigned short* __restrict__ xb,
                                                  const float* __restrict__ x,
                                                  float* __restrict__ xin,
                                                  const int* __restrict__ rs,
                                                  const int* __restrict__ deg,
                                                  const float* __restrict__ dinv,
                                                  const unsigned* __restrict__ csr) {
    int lane = threadIdx.x & 63;
    int node = blockIdx.x * 4 + (threadIdx.x >> 6);
    if (node >= N_NODES) return;
    int cnt = deg[node];
    int start = rs[node];
    float acc0 = 0.f, acc1 = 0.f;
    for (int base = 0; base < cnt; base += 16) {
        int nb = cnt - base;
        if (nb > 16) nb = 16;
        unsigned pk = 0;
        if (lane < nb) pk = csr[start + base + lane];
        unsigned vv[16];
        float mm[16];
        #pragma unroll
        for (int j = 0; j < 16; ++j) {
            unsigned p = (unsigned)__builtin_amdgcn_readlane((int)pk, j);  // 0 for j>=nb
            mm[j] = b2f((unsigned short)(p >> 16));
            vv[j] = *(const unsigned*)(xb + (size_t)(p & 0xFFFFu) * DIM + lane * 2);
        }
        #pragma unroll
        for (int j = 0; j < 16; ++j) {
            acc0 += mm[j] * b2f((unsigned short)(vv[j] & 0xFFFFu));
            acc1 += mm[j] * b2f((unsigned short)(vv[j] >> 16));
        }
    }
    float di = dinv[node];
    float2 xp = *(const float2*)(x + (size_t)node * DIM + lane * 2);
    f32x2_t o;
    o[0] = xp.x + acc0 * di;
    o[1] = xp.y + acc1 * di;
    __builtin_nontemporal_store(o, (f32x2_t*)(xin + (size_t)node * DIM + lane * 2));
}

// ---------------- GEMM [N,128]x[128,128] + BN + ReLU, split-bf16 MFMA ----------------
// B fragments from global fragment-order buffers (L2-resident, no LDS).
// f32 out = NT (read-once next layer); bf16 outb = normal (gather source, wants L2).
__global__ __launch_bounds__(256) void gemm128_bn_relu(const float* __restrict__ xin,
                                                       const unsigned short* __restrict__ wfh,
                                                       const unsigned short* __restrict__ wfl,
                                                       const float* __restrict__ bias,
                                                       const float* __restrict__ gam,
                                                       const float* __restrict__ bet,
                                                       const float* __restrict__ rm,
                                                       const float* __restrict__ rv,
                                                       float* __restrict__ out,
                                                       unsigned short* __restrict__ outb) {
    int tid = threadIdx.x;
    int wave = tid >> 6, lane = tid & 63;
    int m = lane & 15, quad = lane >> 4;
    int rbase = blockIdx.x * 64 + wave * 16;
    int arow = rbase + m;
    const float* ap = xin + (size_t)(arow < N_NODES ? arow : 0) * DIM;

    us8_t ah[4], al[4];
    #pragma unroll
    for (int kt = 0; kt < 4; ++kt) {
        f32x4_t p0 = *(const f32x4_t*)(ap + kt * 32 + quad * 8);
        f32x4_t p1 = *(const f32x4_t*)(ap + kt * 32 + quad * 8 + 4);
        #pragma unroll
        for (int j = 0; j < 4; ++j) {
            unsigned short h0 = f2b(p0[j]);
            unsigned short h1 = f2b(p1[j]);
            ah[kt][j] = h0;
            ah[kt][4 + j] = h1;
            al[kt][j] = f2b(p0[j] - b2f(h0));
            al[kt][4 + j] = f2b(p1[j] - b2f(h1));
        }
    }

    f32x4_t acc[8] = {};
    #pragma unroll
    for (int kt = 0; kt < 4; ++kt) {
        #pragma unroll
        for (int nt = 0; nt < 8; ++nt) {
            int boff = ((nt * 4 + kt) * 64 + lane) * 8;
            us8_t bh = *(const us8_t*)(wfh + boff);
            us8_t bl = *(const us8_t*)(wfl + boff);
            acc[nt] = __builtin_amdgcn_mfma_f32_16x16x32_bf16(
                __builtin_bit_cast(bf16x8_t, ah[kt]),
                __builtin_bit_cast(bf16x8_t, bh), acc[nt], 0, 0, 0);
            acc[nt] = __builtin_amdgcn_mfma_f32_16x16x32_bf16(
                __builtin_bit_cast(bf16x8_t, ah[kt]),
                __builtin_bit_cast(bf16x8_t, bl), acc[nt], 0, 0, 0);
            acc[nt] = __builtin_amdgcn_mfma_f32_16x16x32_bf16(
                __builtin_bit_cast(bf16x8_t, al[kt]),
                __builtin_bit_cast(bf16x8_t, bh), acc[nt], 0, 0, 0);
        }
    }

    #pragma unroll
    for (int nt = 0; nt < 8; ++nt) {
        int j = nt * 16 + m;
        float bj = bias[j];
        float sc = gam[j] * rsqrtf(rv[j] + 1e-5f);
        float sh = bet[j] - rm[j] * sc;
        #pragma unroll
        for (int i = 0; i < 4; ++i) {
            int r = rbase + quad * 4 + i;
            if (r < N_NODES) {
                float z = fmaxf((acc[nt][i] + bj) * sc + sh, 0.f);
                __builtin_nontemporal_store(z, out + (size_t)r * DIM + j);
                outb[(size_t)r * DIM + j] = f2b(z);
            }
        }
    }
}

// ---------------- fused final: h3 = relu(BN((h2+agg)@w2+b2)); out = (h2@wp+bp+h3)*0.5 ----------------
__global__ __launch_bounds__(256) void fused_final(const float* __restrict__ xin2,
                                                   const float* __restrict__ h2,
                                                   const unsigned short* __restrict__ f2h,
                                                   const unsigned short* __restrict__ f2l,
                                                   const unsigned short* __restrict__ fph,
                                                   const unsigned short* __restrict__ fpl,
                                                   const float* __restrict__ b2,
                                                   const float* __restrict__ g2,
                                                   const float* __restrict__ be2,
                                                   const float* __restrict__ rm2,
                                                   const float* __restrict__ rv2,
                                                   const float* __restrict__ bp,
                                                   float* __restrict__ out) {
    int tid = threadIdx.x;
    int wave = tid >> 6, lane = tid & 63;
    int m = lane & 15, quad = lane >> 4;
    int rbase = blockIdx.x * 64 + wave * 16;
    int arow = rbase + m;
    size_t rowoff = (size_t)(arow < N_NODES ? arow : 0) * DIM;
    const float* ap2 = xin2 + rowoff;
    const float* aph = h2 + rowoff;

    us8_t a2h[4], a2l[4], ahh[4], ahl[4];
    #pragma unroll
    for (int kt = 0; kt < 4; ++kt) {
        f32x4_t p0 = *(const f32x4_t*)(ap2 + kt * 32 + quad * 8);
        f32x4_t p1 = *(const f32x4_t*)(ap2 + kt * 32 + quad * 8 + 4);
        f32x4_t q0 = *(const f32x4_t*)(aph + kt * 32 + quad * 8);
        f32x4_t q1 = *(const f32x4_t*)(aph + kt * 32 + quad * 8 + 4);
        #pragma unroll
        for (int j = 0; j < 4; ++j) {
            unsigned short h0 = f2b(p0[j]), h1 = f2b(p1[j]);
            a2h[kt][j] = h0; a2h[kt][4 + j] = h1;
            a2l[kt][j] = f2b(p0[j] - b2f(h0));
            a2l[kt][4 + j] = f2b(p1[j] - b2f(h1));
            unsigned short g0 = f2b(q0[j]), g1 = f2b(q1[j]);
            ahh[kt][j] = g0; ahh[kt][4 + j] = g1;
            ahl[kt][j] = f2b(q0[j] - b2f(g0));
            ahl[kt][4 + j] = f2b(q1[j] - b2f(g1));
        }
    }

    f32x4_t acc2[3] = {};
    f32x4_t accp[3] = {};
    #pragma unroll
    for (int kt = 0; kt < 4; ++kt) {
        #pragma unroll
        for (int nt = 0; nt < 3; ++nt) {
            int boff = ((nt * 4 + kt) * 64 + lane) * 8;
            us8_t b2hv = *(const us8_t*)(f2h + boff);
            us8_t b2lv = *(const us8_t*)(f2l + boff);
            us8_t bphv = *(const us8_t*)(fph + boff);
            us8_t bplv = *(const us8_t*)(fpl + boff);
            acc2[nt] = __builtin_amdgcn_mfma_f32_16x16x32_bf16(
                __builtin_bit_cast(bf16x8_t, a2h[kt]),
                __builtin_bit_cast(bf16x8_t, b2hv), acc2[nt], 0, 0, 0);
            acc2[nt] = __builtin_amdgcn_mfma_f32_16x16x32_bf16(
                __builtin_bit_cast(bf16x8_t, a2h[kt]),
                __builtin_bit_cast(bf16x8_t, b2lv), acc2[nt], 0, 0, 0);
            acc2[nt] = __builtin_amdgcn_mfma_f32_16x16x32_bf16(
                __builtin_bit_cast(bf16x8_t, a2l[kt]),
                __builtin_bit_cast(bf16x8_t, b2hv), acc2[nt], 0, 0, 0);
            accp[nt] = __builtin_amdgcn_mfma_f32_16x16x32_bf16(
                __builtin_bit_cast(bf16x8_t, ahh[kt]),
                __builtin_bit_cast(bf16x8_t, bphv), accp[nt], 0, 0, 0);
            accp[nt] = __builtin_amdgcn_mfma_f32_16x16x32_bf16(
                __builtin_bit_cast(bf16x8_t, ahh[kt]),
                __builtin_bit_cast(bf16x8_t, bplv), accp[nt], 0, 0, 0);
            accp[nt] = __builtin_amdgcn_mfma_f32_16x16x32_bf16(
                __builtin_bit_cast(bf16x8_t, ahl[kt]),
                __builtin_bit_cast(bf16x8_t, bphv), accp[nt], 0, 0, 0);
        }
    }

    #pragma unroll
    for (int nt = 0; nt < 3; ++nt) {
        int j = nt * 16 + m;
        int jc = (j < NCLS) ? j : (NCLS - 1);
        float b2j = b2[jc];
        float sc = g2[jc] * rsqrtf(rv2[jc] + 1e-5f);
        float sh = be2[jc] - rm2[jc] * sc;
        float bpj = bp[jc];
        #pragma unroll
        for (int i = 0; i < 4; ++i) {
            int r = rbase + quad * 4 + i;
            if (r < N_NODES && j < NCLS) {
                float z = fmaxf((acc2[nt][i] + b2j) * sc + sh, 0.f);
                float p = accp[nt][i] + bpj;
                out[(size_t)r * NCLS + j] = (p + z) * 0.5f;
            }
        }
    }
}

extern "C" void kernel_launch(void* const* d_in, const int* in_sizes, int n_in,
                              void* d_out, int out_size, void* d_ws, size_t ws_size,
                              hipStream_t stream) {
    const float* h    = (const float*)d_in[0];
    const int* esrc   = (const int*)d_in[1];
    const int* edst   = (const int*)d_in[2];
    const float* mask = (const float*)d_in[3];
    const float* w0   = (const float*)d_in[4];
    const float* b0   = (const float*)d_in[5];
    const float* g0   = (const float*)d_in[6];
    const float* be0  = (const float*)d_in[7];
    const float* rm0  = (const float*)d_in[8];
    const float* rv0  = (const float*)d_in[9];
    const float* w1   = (const float*)d_in[10];
    const float* b1   = (const float*)d_in[11];
    const float* g1   = (const float*)d_in[12];
    const float* be1  = (const float*)d_in[13];
    const float* rm1  = (const float*)d_in[14];
    const float* rv1  = (const float*)d_in[15];
    const float* w2   = (const float*)d_in[16];
    const float* b2   = (const float*)d_in[17];
    const float* g2   = (const float*)d_in[18];
    const float* be2  = (const float*)d_in[19];
    const float* rm2  = (const float*)d_in[20];
    const float* rv2  = (const float*)d_in[21];
    const float* wp   = (const float*)d_in[22];
    const float* bp   = (const float*)d_in[23];

    char* ws = (char*)d_ws;
    size_t off = 0;
    auto alloc = [&](size_t bytes) {
        char* p = ws + off;
        off = (off + bytes + 255) & ~(size_t)255;
        return p;
    };
    int* rs       = (int*)alloc(N_PAD * 4);
    int* deg      = (int*)alloc(N_PAD * 4);
    float* dinv   = (float*)alloc(N_PAD * 4);
    int* partial  = (int*)alloc(128 * 4);
    unsigned* degp = (unsigned*)alloc(2 * WHALF * 4);
    unsigned* csr = (unsigned*)alloc((size_t)N_EDGES * 4);
    unsigned short* ranks = (unsigned short*)alloc((size_t)N_EDGES * 2);
    float* xin    = (float*)alloc((size_t)N_NODES * DIM * 4);
    float* hb     = (float*)alloc((size_t)N_NODES * DIM * 4);
    unsigned short* xb16 = (unsigned short*)alloc((size_t)N_NODES * DIM * 2);
    unsigned short* hb16 = (unsigned short*)alloc((size_t)N_NODES * DIM * 2);
    unsigned short* f0h = (unsigned short*)alloc(16384 * 2);
    unsigned short* f0l = (unsigned short*)alloc(16384 * 2);
    unsigned short* f1h = (unsigned short*)alloc(16384 * 2);
    unsigned short* f1l = (unsigned short*)alloc(16384 * 2);
    unsigned short* f2h = (unsigned short*)alloc(6144 * 2);
    unsigned short* f2l = (unsigned short*)alloc(6144 * 2);
    unsigned short* fph = (unsigned short*)alloc(6144 * 2);
    unsigned short* fpl = (unsigned short*)alloc(6144 * 2);
    // cnt (6.4 MB) aliases xin (25.6 MB): fully consumed by fill3 before agg writes xin
    unsigned* cnt = (unsigned*)xin;

    const int EB = (N_EDGES + 255) / 256;   // 3125
    const int AB = (N_NODES + 3) / 4;
    const int GB = (N_NODES + 63) / 64;

    prep<<<3301, 256, 0, stream>>>(h, xb16, w0, w1, w2, wp,
                                   f0h, f0l, f1h, f1l, f2h, f2l, fph, fpl);
    chunk_count<<<dim3(NCHUNK, 2), 256, 0, stream>>>(edst, cnt, ranks);
    cscan<<<SCAN_B, 256, 0, stream>>>(cnt, degp, partial);
    scan_final<<<SCAN_B, 256, 0, stream>>>(degp, partial, rs, deg, dinv);
    fill3<<<EB, 256, 0, stream>>>(esrc, edst, mask, cnt, rs, ranks, csr);

    // layer 0
    agg_kernel<<<AB, 256, 0, stream>>>(xb16, h, xin, rs, deg, dinv, csr);
    gemm128_bn_relu<<<GB, 256, 0, stream>>>(xin, f0h, f0l, b0, g0, be0, rm0, rv0, hb, hb16);
    // layer 1
    agg_kernel<<<AB, 256, 0, stream>>>(hb16, hb, xin, rs, deg, dinv, csr);
    gemm128_bn_relu<<<GB, 256, 0, stream>>>(xin, f1h, f1l, b1, g1, be1, rm1, rv1, hb, hb16);
    // layer 2 + predict, fused
    agg_kernel<<<AB, 256, 0, stream>>>(hb16, hb, xin, rs, deg, dinv, csr);
    fused_final<<<GB, 256, 0, stream>>>(xin, hb, f2h, f2l, fph, fpl,
                                        b2, g2, be2, rm2, rv2, bp, (float*)d_out);
}

// Round 14
// 329.745 us; speedup vs baseline: 1.0378x; 1.0378x over previous
//
#include <hip/hip_runtime.h>

#define N_NODES 50000
#define N_EDGES 800000
#define DIM 128
#define NCLS 40

// chunked CSR build
#define NCHUNK 128
#define CE 6250            // NCHUNK*CE == N_EDGES exactly
#define HALF_N 25088       // nodes per half (2*WHALF)
#define WHALF 12544        // packed u32 words per half (= 49*256)
#define SCAN_B 98          // cscan/scan_final blocks (2 halves * 49)
#define N_PAD 50432        // >= 2*HALF_N padded node arrays

typedef __bf16 bf16x8_t __attribute__((ext_vector_type(8)));
typedef unsigned short us8_t __attribute__((ext_vector_type(8)));
typedef float f32x4_t __attribute__((ext_vector_type(4)));

static __device__ __forceinline__ float b2f(unsigned short h) {
    unsigned u = ((unsigned)h) << 16;
    return __builtin_bit_cast(float, u);
}
static __device__ __forceinline__ unsigned short f2b(float f) {
    unsigned u = __builtin_bit_cast(unsigned, f);
    u += 0x7FFFu + ((u >> 16) & 1u);   // RNE; values finite O(1)
    return (unsigned short)(u >> 16);
}

// ---------------- f32 -> bf16 shadow of h ----------------
__global__ __launch_bounds__(256) void to_bf16(const float* __restrict__ in,
                                               unsigned short* __restrict__ out) {
    size_t e0 = ((size_t)blockIdx.x * 256 + threadIdx.x) * 8;   // 3125*256*8 = 6.4M exact
    f32x4_t v0 = *(const f32x4_t*)(in + e0);
    f32x4_t v1 = *(const f32x4_t*)(in + e0 + 4);
    us8_t o;
    #pragma unroll
    for (int j = 0; j < 4; ++j) { o[j] = f2b(v0[j]); o[4 + j] = f2b(v1[j]); }
    *(us8_t*)(out + e0) = o;
}

// ---------------- one-time weight repack into MFMA fragment order (global) ----------------
// frag offset for (k,n): nt=n>>4,m=n&15,kt=k>>5,quad=(k>>3)&3,j=k&7
//   off = ((nt*4+kt)*64 + quad*16 + m)*8 + j   -> lane L=quad*16+m reads chunk L contiguous
__global__ __launch_bounds__(256) void repack_w(const float* __restrict__ w0,
                                                const float* __restrict__ w1,
                                                const float* __restrict__ w2,
                                                const float* __restrict__ wp,
                                                unsigned short* __restrict__ f0h,
                                                unsigned short* __restrict__ f0l,
                                                unsigned short* __restrict__ f1h,
                                                unsigned short* __restrict__ f1l,
                                                unsigned short* __restrict__ f2h,
                                                unsigned short* __restrict__ f2l,
                                                unsigned short* __restrict__ fph,
                                                unsigned short* __restrict__ fpl) {
    int t = blockIdx.x * 256 + threadIdx.x;
    const float* src;
    unsigned short *dh, *dl;
    int idx, ncols;
    if (t < 16384)      { src = w0; dh = f0h; dl = f0l; idx = t;         ncols = 128; }
    else if (t < 32768) { src = w1; dh = f1h; dl = f1l; idx = t - 16384; ncols = 128; }
    else if (t < 38912) { src = w2; dh = f2h; dl = f2l; idx = t - 32768; ncols = 48; }
    else if (t < 45056) { src = wp; dh = fph; dl = fpl; idx = t - 38912; ncols = 48; }
    else return;
    int k = idx / ncols, n = idx - k * ncols;
    float v;
    if (ncols == 128) v = src[k * 128 + n];
    else              v = (n < NCLS) ? src[k * NCLS + n] : 0.f;
    int nt = n >> 4, m = n & 15, kt = k >> 5, quad = (k >> 3) & 3, j = k & 7;
    int off = ((nt * 4 + kt) * 64 + quad * 16 + m) * 8 + j;
    unsigned short hi = f2b(v);
    dh[off] = hi;
    dl[off] = f2b(v - b2f(hi));
}

// ---------------- per-chunk per-node edge counts (LDS atomics); blockIdx.y = half ----------------
__global__ __launch_bounds__(256) void chunk_count(const int* __restrict__ dst,
                                                   unsigned* __restrict__ cnt) {
    __shared__ unsigned lds[WHALF];   // 50 KB
    int c = blockIdx.x, h = blockIdx.y, tid = threadIdx.x;
    for (int w = tid; w < WHALF; w += 256) lds[w] = 0;
    __syncthreads();
    int base = c * CE;
    for (int k = tid; k < CE; k += 256) {
        int local = dst[base + k] - h * HALF_N;
        if (local >= 0 && local < HALF_N)
            atomicAdd(&lds[local >> 1], 1u << ((local & 1) * 16));
    }
    __syncthreads();
    unsigned* out = cnt + ((size_t)(h * NCHUNK + c)) * WHALF;
    for (int w = tid; w < WHALF; w += 256) out[w] = lds[w];
}

// ---------------- scan over chunk axis ----------------
__global__ __launch_bounds__(256) void cscan(unsigned* __restrict__ cnt,
                                             unsigned* __restrict__ degp,
                                             int* __restrict__ partial) {
    __shared__ int lds[256];
    int b = blockIdx.x;
    int h = b / 49;
    int w = (b % 49) * 256 + threadIdx.x;
    unsigned acc = 0;
    for (int c = 0; c < NCHUNK; ++c) {
        size_t idx = ((size_t)(h * NCHUNK + c)) * WHALF + w;
        unsigned v = cnt[idx];
        cnt[idx] = acc;          // exclusive prefix (packed halves)
        acc += v;
    }
    degp[h * WHALF + w] = acc;
    lds[threadIdx.x] = (int)(acc & 0xFFFFu) + (int)(acc >> 16);
    __syncthreads();
    #pragma unroll
    for (int off = 128; off > 0; off >>= 1) {
        if (threadIdx.x < off) lds[threadIdx.x] += lds[threadIdx.x + off];
        __syncthreads();
    }
    if (threadIdx.x == 0) partial[b] = lds[0];
}

__global__ __launch_bounds__(128) void scan_blocks(const int* __restrict__ partial,
                                                   int* __restrict__ blk_off) {
    __shared__ int lds[128];
    int tid = threadIdx.x;
    lds[tid] = (tid < SCAN_B) ? partial[tid] : 0;
    __syncthreads();
    #pragma unroll
    for (int off = 1; off < 128; off <<= 1) {
        int v = lds[tid];
        int add = (tid >= off) ? lds[tid - off] : 0;
        __syncthreads();
        lds[tid] = v + add;
        __syncthreads();
    }
    if (tid < SCAN_B) blk_off[tid] = (tid == 0) ? 0 : lds[tid - 1];
}

// ---------------- final node-axis scan: rs / deg / dinv ----------------
__global__ __launch_bounds__(256) void scan_final(const unsigned* __restrict__ degp,
                                                  const int* __restrict__ blk_off,
                                                  int* __restrict__ rs,
                                                  int* __restrict__ deg,
                                                  float* __restrict__ dinv) {
    __shared__ int lds[256];
    int b = blockIdx.x;
    int h = b / 49;
    int tid = threadIdx.x;
    int w = (b % 49) * 256 + tid;
    unsigned dp = degp[h * WHALF + w];
    int lo = (int)(dp & 0xFFFFu), hi = (int)(dp >> 16);
    int s = lo + hi;
    lds[tid] = s;
    __syncthreads();
    #pragma unroll
    for (int off = 1; off < 256; off <<= 1) {
        int v = lds[tid];
        int add = (tid >= off) ? lds[tid - off] : 0;
        __syncthreads();
        lds[tid] = v + add;
        __syncthreads();
    }
    int excl = blk_off[b] + lds[tid] - s;
    int n0 = h * HALF_N + 2 * w;
    rs[n0] = excl;
    rs[n0 + 1] = excl + lo;
    deg[n0] = lo;
    deg[n0 + 1] = hi;
    dinv[n0] = (lo > 0) ? (1.0f / (float)lo) : 0.0f;
    dinv[n0 + 1] = (hi > 0) ? (1.0f / (float)hi) : 0.0f;
}

// ---------------- CSR fill: rank via LDS returning atomics; blockIdx.y = half ----------------
__global__ __launch_bounds__(256) void fill2(const int* __restrict__ src,
                                             const int* __restrict__ dst,
                                             const float* __restrict__ mask,
                                             const unsigned* __restrict__ cnt,
                                             const int* __restrict__ rs,
                                             unsigned* __restrict__ csr) {
    __shared__ unsigned cur[WHALF];   // 50 KB
    int c = blockIdx.x, h = blockIdx.y, tid = threadIdx.x;
    const unsigned* off = cnt + ((size_t)(h * NCHUNK + c)) * WHALF;
    for (int w = tid; w < WHALF; w += 256) cur[w] = off[w];
    __syncthreads();
    int base = c * CE;
    for (int k = tid; k < CE; k += 256) {
        int e = base + k;
        int d = dst[e];
        int local = d - h * HALF_N;
        if (local >= 0 && local < HALF_N) {
            unsigned sm = (unsigned)src[e] | ((unsigned)f2b(mask[e]) << 16);
            int sh = (local & 1) * 16;
            unsigned old = atomicAdd(&cur[local >> 1], 1u << sh);
            int rank = (int)((old >> sh) & 0xFFFFu);
            csr[rs[d] + rank] = sm;
        }
    }
}

// ---------------- mean aggregation: bf16 gather + f32 residual (batch-16) ----------------
__global__ __launch_bounds__(256) void agg_kernel(const unsigned short* __restrict__ xb,
                                                  const float* __restrict__ x,
                                                  float* __restrict__ xin,
                                                  const int* __restrict__ rs,
                                                  const int* __restrict__ deg,
                                                  const float* __restrict__ dinv,
                                                  const unsigned* __restrict__ csr) {
    int lane = threadIdx.x & 63;
    int node = blockIdx.x * 4 + (threadIdx.x >> 6);
    if (node >= N_NODES) return;
    int cnt = deg[node];
    int start = rs[node];
    float acc0 = 0.f, acc1 = 0.f;
    for (int base = 0; base < cnt; base += 16) {
        int nb = cnt - base;
        if (nb > 16) nb = 16;
        unsigned pk = 0;
        if (lane < nb) pk = csr[start + base + lane];
        unsigned vv[16];
        float mm[16];
        #pragma unroll
        for (int j = 0; j < 16; ++j) {
            unsigned p = (unsigned)__builtin_amdgcn_readlane((int)pk, j);  // 0 for j>=nb
            mm[j] = b2f((unsigned short)(p >> 16));
            vv[j] = *(const unsigned*)(xb + (size_t)(p & 0xFFFFu) * DIM + lane * 2);
        }
        #pragma unroll
        for (int j = 0; j < 16; ++j) {
            acc0 += mm[j] * b2f((unsigned short)(vv[j] & 0xFFFFu));
            acc1 += mm[j] * b2f((unsigned short)(vv[j] >> 16));
        }
    }
    float di = dinv[node];
    float2 xp = *(const float2*)(x + (size_t)node * DIM + lane * 2);
    float2 o;
    o.x = xp.x + acc0 * di;
    o.y = xp.y + acc1 * di;
    *(float2*)(xin + (size_t)node * DIM + lane * 2) = o;
}

// ---------------- GEMM [N,128]x[128,128] + BN + ReLU, split-bf16 MFMA ----------------
// B fragments loaded straight from global fragment-order buffers (L2-resident, no LDS)
__global__ __launch_bounds__(256) void gemm128_bn_relu(const float* __restrict__ xin,
                                                       const unsigned short* __restrict__ wfh,
                                                       const unsigned short* __restrict__ wfl,
                                                       const float* __restrict__ bias,
                                                       const float* __restrict__ gam,
                                                       const float* __restrict__ bet,
                                                       const float* __restrict__ rm,
                                                       const float* __restrict__ rv,
                                                       float* __restrict__ out,
                                                       unsigned short* __restrict__ outb) {
    int tid = threadIdx.x;
    int wave = tid >> 6, lane = tid & 63;
    int m = lane & 15, quad = lane >> 4;
    int rbase = blockIdx.x * 64 + wave * 16;
    int arow = rbase + m;
    const float* ap = xin + (size_t)(arow < N_NODES ? arow : 0) * DIM;

    us8_t ah[4], al[4];
    #pragma unroll
    for (int kt = 0; kt < 4; ++kt) {
        f32x4_t p0 = *(const f32x4_t*)(ap + kt * 32 + quad * 8);
        f32x4_t p1 = *(const f32x4_t*)(ap + kt * 32 + quad * 8 + 4);
        #pragma unroll
        for (int j = 0; j < 4; ++j) {
            unsigned short h0 = f2b(p0[j]);
            unsigned short h1 = f2b(p1[j]);
            ah[kt][j] = h0;
            ah[kt][4 + j] = h1;
            al[kt][j] = f2b(p0[j] - b2f(h0));
            al[kt][4 + j] = f2b(p1[j] - b2f(h1));
        }
    }

    f32x4_t acc[8] = {};
    #pragma unroll
    for (int kt = 0; kt < 4; ++kt) {
        #pragma unroll
        for (int nt = 0; nt < 8; ++nt) {
            int boff = ((nt * 4 + kt) * 64 + lane) * 8;
            us8_t bh = *(const us8_t*)(wfh + boff);
            us8_t bl = *(const us8_t*)(wfl + boff);
            acc[nt] = __builtin_amdgcn_mfma_f32_16x16x32_bf16(
                __builtin_bit_cast(bf16x8_t, ah[kt]),
                __builtin_bit_cast(bf16x8_t, bh), acc[nt], 0, 0, 0);
            acc[nt] = __builtin_amdgcn_mfma_f32_16x16x32_bf16(
                __builtin_bit_cast(bf16x8_t, ah[kt]),
                __builtin_bit_cast(bf16x8_t, bl), acc[nt], 0, 0, 0);
            acc[nt] = __builtin_amdgcn_mfma_f32_16x16x32_bf16(
                __builtin_bit_cast(bf16x8_t, al[kt]),
                __builtin_bit_cast(bf16x8_t, bh), acc[nt], 0, 0, 0);
        }
    }

    #pragma unroll
    for (int nt = 0; nt < 8; ++nt) {
        int j = nt * 16 + m;
        float bj = bias[j];
        float sc = gam[j] * rsqrtf(rv[j] + 1e-5f);
        float sh = bet[j] - rm[j] * sc;
        #pragma unroll
        for (int i = 0; i < 4; ++i) {
            int r = rbase + quad * 4 + i;
            if (r < N_NODES) {
                float z = fmaxf((acc[nt][i] + bj) * sc + sh, 0.f);
                out[(size_t)r * DIM + j] = z;
                outb[(size_t)r * DIM + j] = f2b(z);
            }
        }
    }
}

// ---------------- fused final: h3 = relu(BN((h2+agg)@w2+b2)); out = (h2@wp+bp+h3)*0.5 ----------------
__global__ __launch_bounds__(256) void fused_final(const float* __restrict__ xin2,
                                                   const float* __restrict__ h2,
                                                   const unsigned short* __restrict__ f2h,
                                                   const unsigned short* __restrict__ f2l,
                                                   const unsigned short* __restrict__ fph,
                                                   const unsigned short* __restrict__ fpl,
                                                   const float* __restrict__ b2,
                                                   const float* __restrict__ g2,
                                                   const float* __restrict__ be2,
                                                   const float* __restrict__ rm2,
                                                   const float* __restrict__ rv2,
                                                   const float* __restrict__ bp,
                                                   float* __restrict__ out) {
    int tid = threadIdx.x;
    int wave = tid >> 6, lane = tid & 63;
    int m = lane & 15, quad = lane >> 4;
    int rbase = blockIdx.x * 64 + wave * 16;
    int arow = rbase + m;
    size_t rowoff = (size_t)(arow < N_NODES ? arow : 0) * DIM;
    const float* ap2 = xin2 + rowoff;
    const float* aph = h2 + rowoff;

    us8_t a2h[4], a2l[4], ahh[4], ahl[4];
    #pragma unroll
    for (int kt = 0; kt < 4; ++kt) {
        f32x4_t p0 = *(const f32x4_t*)(ap2 + kt * 32 + quad * 8);
        f32x4_t p1 = *(const f32x4_t*)(ap2 + kt * 32 + quad * 8 + 4);
        f32x4_t q0 = *(const f32x4_t*)(aph + kt * 32 + quad * 8);
        f32x4_t q1 = *(const f32x4_t*)(aph + kt * 32 + quad * 8 + 4);
        #pragma unroll
        for (int j = 0; j < 4; ++j) {
            unsigned short h0 = f2b(p0[j]), h1 = f2b(p1[j]);
            a2h[kt][j] = h0; a2h[kt][4 + j] = h1;
            a2l[kt][j] = f2b(p0[j] - b2f(h0));
            a2l[kt][4 + j] = f2b(p1[j] - b2f(h1));
            unsigned short g0 = f2b(q0[j]), g1 = f2b(q1[j]);
            ahh[kt][j] = g0; ahh[kt][4 + j] = g1;
            ahl[kt][j] = f2b(q0[j] - b2f(g0));
            ahl[kt][4 + j] = f2b(q1[j] - b2f(g1));
        }
    }

    f32x4_t acc2[3] = {};
    f32x4_t accp[3] = {};
    #pragma unroll
    for (int kt = 0; kt < 4; ++kt) {
        #pragma unroll
        for (int nt = 0; nt < 3; ++nt) {
            int boff = ((nt * 4 + kt) * 64 + lane) * 8;
            us8_t b2hv = *(const us8_t*)(f2h + boff);
            us8_t b2lv = *(const us8_t*)(f2l + boff);
            us8_t bphv = *(const us8_t*)(fph + boff);
            us8_t bplv = *(const us8_t*)(fpl + boff);
            acc2[nt] = __builtin_amdgcn_mfma_f32_16x16x32_bf16(
                __builtin_bit_cast(bf16x8_t, a2h[kt]),
                __builtin_bit_cast(bf16x8_t, b2hv), acc2[nt], 0, 0, 0);
            acc2[nt] = __builtin_amdgcn_mfma_f32_16x16x32_bf16(
                __builtin_bit_cast(bf16x8_t, a2h[kt]),
                __builtin_bit_cast(bf16x8_t, b2lv), acc2[nt], 0, 0, 0);
            acc2[nt] = __builtin_amdgcn_mfma_f32_16x16x32_bf16(
                __builtin_bit_cast(bf16x8_t, a2l[kt]),
                __builtin_bit_cast(bf16x8_t, b2hv), acc2[nt], 0, 0, 0);
            accp[nt] = __builtin_amdgcn_mfma_f32_16x16x32_bf16(
                __builtin_bit_cast(bf16x8_t, ahh[kt]),
                __builtin_bit_cast(bf16x8_t, bphv), accp[nt], 0, 0, 0);
            accp[nt] = __builtin_amdgcn_mfma_f32_16x16x32_bf16(
                __builtin_bit_cast(bf16x8_t, ahh[kt]),
                __builtin_bit_cast(bf16x8_t, bplv), accp[nt], 0, 0, 0);
            accp[nt] = __builtin_amdgcn_mfma_f32_16x16x32_bf16(
                __builtin_bit_cast(bf16x8_t, ahl[kt]),
                __builtin_bit_cast(bf16x8_t, bphv), accp[nt], 0, 0, 0);
        }
    }

    #pragma unroll
    for (int nt = 0; nt < 3; ++nt) {
        int j = nt * 16 + m;
        int jc = (j < NCLS) ? j : (NCLS - 1);
        float b2j = b2[jc];
        float sc = g2[jc] * rsqrtf(rv2[jc] + 1e-5f);
        float sh = be2[jc] - rm2[jc] * sc;
        float bpj = bp[jc];
        #pragma unroll
        for (int i = 0; i < 4; ++i) {
            int r = rbase + quad * 4 + i;
            if (r < N_NODES && j < NCLS) {
                float z = fmaxf((acc2[nt][i] + b2j) * sc + sh, 0.f);
                float p = accp[nt][i] + bpj;
                out[(size_t)r * NCLS + j] = (p + z) * 0.5f;
            }
        }
    }
}

extern "C" void kernel_launch(void* const* d_in, const int* in_sizes, int n_in,
                              void* d_out, int out_size, void* d_ws, size_t ws_size,
                              hipStream_t stream) {
    const float* h    = (const float*)d_in[0];
    const int* esrc   = (const int*)d_in[1];
    const int* edst   = (const int*)d_in[2];
    const float* mask = (const float*)d_in[3];
    const float* w0   = (const float*)d_in[4];
    const float* b0   = (const float*)d_in[5];
    const float* g0   = (const float*)d_in[6];
    const float* be0  = (const float*)d_in[7];
    const float* rm0  = (const float*)d_in[8];
    const float* rv0  = (const float*)d_in[9];
    const float* w1   = (const float*)d_in[10];
    const float* b1   = (const float*)d_in[11];
    const float* g1   = (const float*)d_in[12];
    const float* be1  = (const float*)d_in[13];
    const float* rm1  = (const float*)d_in[14];
    const float* rv1  = (const float*)d_in[15];
    const float* w2   = (const float*)d_in[16];
    const float* b2   = (const float*)d_in[17];
    const float* g2   = (const float*)d_in[18];
    const float* be2  = (const float*)d_in[19];
    const float* rm2  = (const float*)d_in[20];
    const float* rv2  = (const float*)d_in[21];
    const float* wp   = (const float*)d_in[22];
    const float* bp   = (const float*)d_in[23];

    char* ws = (char*)d_ws;
    size_t off = 0;
    auto alloc = [&](size_t bytes) {
        char* p = ws + off;
        off = (off + bytes + 255) & ~(size_t)255;
        return p;
    };
    int* rs       = (int*)alloc(N_PAD * 4);
    int* deg      = (int*)alloc(N_PAD * 4);
    float* dinv   = (float*)alloc(N_PAD * 4);
    int* partial  = (int*)alloc(128 * 4);
    int* blk_off  = (int*)alloc(128 * 4);
    unsigned* degp = (unsigned*)alloc(2 * WHALF * 4);
    unsigned* csr = (unsigned*)alloc((size_t)N_EDGES * 4);
    float* xin    = (float*)alloc((size_t)N_NODES * DIM * 4);
    float* hb     = (float*)alloc((size_t)N_NODES * DIM * 4);
    unsigned short* xb16 = (unsigned short*)alloc((size_t)N_NODES * DIM * 2);
    unsigned short* hb16 = (unsigned short*)alloc((size_t)N_NODES * DIM * 2);
    unsigned short* f0h = (unsigned short*)alloc(16384 * 2);
    unsigned short* f0l = (unsigned short*)alloc(16384 * 2);
    unsigned short* f1h = (unsigned short*)alloc(16384 * 2);
    unsigned short* f1l = (unsigned short*)alloc(16384 * 2);
    unsigned short* f2h = (unsigned short*)alloc(6144 * 2);
    unsigned short* f2l = (unsigned short*)alloc(6144 * 2);
    unsigned short* fph = (unsigned short*)alloc(6144 * 2);
    unsigned short* fpl = (unsigned short*)alloc(6144 * 2);
    // cnt (12.85 MB) aliases xin (25.6 MB): fully consumed by fill2 before agg writes xin
    unsigned* cnt = (unsigned*)xin;

    const int AB = (N_NODES + 3) / 4;
    const int GB = (N_NODES + 63) / 64;

    to_bf16<<<3125, 256, 0, stream>>>(h, xb16);
    repack_w<<<176, 256, 0, stream>>>(w0, w1, w2, wp, f0h, f0l, f1h, f1l,
                                      f2h, f2l, fph, fpl);
    chunk_count<<<dim3(NCHUNK, 2), 256, 0, stream>>>(edst, cnt);
    cscan<<<SCAN_B, 256, 0, stream>>>(cnt, degp, partial);
    scan_blocks<<<1, 128, 0, stream>>>(partial, blk_off);
    scan_final<<<SCAN_B, 256, 0, stream>>>(degp, blk_off, rs, deg, dinv);
    fill2<<<dim3(NCHUNK, 2), 256, 0, stream>>>(esrc, edst, mask, cnt, rs, csr);

    // layer 0
    agg_kernel<<<AB, 256, 0, stream>>>(xb16, h, xin, rs, deg, dinv, csr);
    gemm128_bn_relu<<<GB, 256, 0, stream>>>(xin, f0h, f0l, b0, g0, be0, rm0, rv0, hb, hb16);
    // layer 1
    agg_kernel<<<AB, 256, 0, stream>>>(hb16, hb, xin, rs, deg, dinv, csr);
    gemm128_bn_relu<<<GB, 256, 0, stream>>>(xin, f1h, f1l, b1, g1, be1, rm1, rv1, hb, hb16);
    // layer 2 + predict, fused
    agg_kernel<<<AB, 256, 0, stream>>>(hb16, hb, xin, rs, deg, dinv, csr);
    fused_final<<<GB, 256, 0, stream>>>(xin, hb, f2h, f2l, fph, fpl,
                                        b2, g2, be2, rm2, rv2, bp, (float*)d_out);
}